// Round 1
// baseline (80.912 us; speedup 1.0000x reference)
//
#include <hip/hip_runtime.h>
#include <hip/hip_bf16.h>

typedef float f32x4 __attribute__((ext_vector_type(4)));
typedef short s16x8 __attribute__((ext_vector_type(8)));
typedef short s16x4 __attribute__((ext_vector_type(4)));

#define N_NODES 768
#define NODE_DIM_ 256
#define HDIM 64
#define EDIM 128
#define CTILES 48                       // 768 / 16
#define TILES_TOTAL (N_NODES * CTILES)  // 36864

static __device__ __forceinline__ short f2bf(float f) {
    __hip_bfloat16 h = __float2bfloat16(f);
    return __builtin_bit_cast(short, h);
}

// ---------------- Kernel 1: n_i = x@Wi + bi, n_j = x@Wj + bj ----------------
__global__ __launch_bounds__(256) void proj_kernel(
        const float* __restrict__ x,
        const float* __restrict__ Wi, const float* __restrict__ bi,
        const float* __restrict__ Wj, const float* __restrict__ bj,
        float* __restrict__ NI, float* __restrict__ NJ) {
    int row  = blockIdx.x * 4 + (threadIdx.x >> 6);
    int lane = threadIdx.x & 63;
    float ai = bi[lane];
    float aj = bj[lane];
    const float* xr = x + row * NODE_DIM_;
#pragma unroll 8
    for (int k = 0; k < NODE_DIM_; ++k) {
        float xv = xr[k];
        ai = fmaf(xv, Wi[k * HDIM + lane], ai);
        aj = fmaf(xv, Wj[k * HDIM + lane], aj);
    }
    NI[row * HDIM + lane] = ai;
    NJ[row * HDIM + lane] = aj;
}

// ---------------- Kernel 2: pairwise LN -> GEMM1(relu) -> GEMM2 ----------------
// Per wave-tile: a fixed, 16 consecutive c. MFMA 16x16x32 bf16.
// A/B frag: lane l holds (row/col = l&15), k = (l>>4)*8 + j  (j = 0..7)
// C/D: lane l holds col = l&15, row = (l>>4)*4 + r           (r = 0..3)
__global__ __launch_bounds__(256) void edge_kernel(
        const float* __restrict__ NI, const float* __restrict__ NJ,
        const float* __restrict__ lng, const float* __restrict__ lnb,
        const float* __restrict__ W1, const float* __restrict__ b1,
        const float* __restrict__ W2, const float* __restrict__ b2,
        float* __restrict__ out) {
    __shared__ short W1L[4096];     // [(kh*4+hi)][n(64)][j(8)]  bf16
    __shared__ short W2L[8192];     // [(kh*4+hi)][n(128)][j(8)] bf16
    __shared__ short TL[4][1024];   // per-wave t tile [16][64] bf16, XOR-swizzled

    // Stage W1/W2 as bf16 in B-frag-friendly layout (once per block)
    for (int idx = threadIdx.x; idx < 4096; idx += 256) {
        int k = idx >> 6, n = idx & 63;
        W1L[(k >> 3) * 512 + n * 8 + (k & 7)] = f2bf(W1[idx]);
    }
    for (int idx = threadIdx.x; idx < 8192; idx += 256) {
        int k = idx >> 7, n = idx & 127;
        W2L[(k >> 3) * 1024 + n * 8 + (k & 7)] = f2bf(W2[idx]);
    }
    __syncthreads();

    const int wave = threadIdx.x >> 6;
    const int lane = threadIdx.x & 63;
    const int l15  = lane & 15;
    const int hi   = lane >> 4;
    const int swz  = (l15 & 7) << 4;   // bank swizzle for the 128B-stride t tile

    // LN gamma/beta for this lane's 16 h-columns (cols hi*8+j and 32+hi*8+j)
    float gl[8], gh[8], bl[8], bh[8];
#pragma unroll
    for (int j = 0; j < 8; ++j) {
        gl[j] = lng[hi * 8 + j];      gh[j] = lng[32 + hi * 8 + j];
        bl[j] = lnb[hi * 8 + j];      bh[j] = lnb[32 + hi * 8 + j];
    }
    // b1 for t^T acc layout: col = nt*16 + hi*4 + r
    float b1v[16];
#pragma unroll
    for (int nt = 0; nt < 4; ++nt)
#pragma unroll
        for (int r = 0; r < 4; ++r)
            b1v[nt * 4 + r] = b1[nt * 16 + hi * 4 + r];
    // b2 for out acc layout: col = nt*16 + l15
    float b2v[8];
#pragma unroll
    for (int nt = 0; nt < 8; ++nt)
        b2v[nt] = b2[nt * 16 + l15];

    char* tl = (char*)&TL[wave][0];

    const int wid = blockIdx.x * 4 + wave;
    const int nw  = gridDim.x * 4;
    for (int t = wid; t < TILES_TOTAL; t += nw) {
        int a  = t / CTILES;
        int c0 = (t - a * CTILES) * 16;

        // v = n_i[c0+l15] + n_j[a], this lane's 16 columns
        const float* nip = NI + (c0 + l15) * HDIM + hi * 8;
        const float* njp = NJ + a * HDIM + hi * 8;
        float v[16];
#pragma unroll
        for (int j = 0; j < 8; ++j) {
            v[j]     = nip[j]      + njp[j];
            v[8 + j] = nip[32 + j] + njp[32 + j];
        }
        // LayerNorm stats: lanes l, l^16, l^32, l^48 share a row
        float s = 0.f, ss = 0.f;
#pragma unroll
        for (int j = 0; j < 16; ++j) { s += v[j]; ss = fmaf(v[j], v[j], ss); }
        s += __shfl_xor(s, 16);  ss += __shfl_xor(ss, 16);
        s += __shfl_xor(s, 32);  ss += __shfl_xor(ss, 32);
        float mu   = s * (1.f / 64.f);
        float var  = ss * (1.f / 64.f) - mu * mu;
        float rstd = rsqrtf(var + 1e-5f);

        // h fragments (B-frag of h^T == A-frag mapping): row l15, k = hi*8+j (+32)
        s16x8 hf0, hf1;
#pragma unroll
        for (int j = 0; j < 8; ++j) {
            hf0[j] = f2bf(fmaf((v[j]     - mu) * rstd, gl[j], bl[j]));
            hf1[j] = f2bf(fmaf((v[8 + j] - mu) * rstd, gh[j], bh[j]));
        }

        // GEMM1, operand-swapped: acc = W1^T-tile * h^T  => lane holds
        // t[row=l15][col = nt*16 + hi*4 + r]  -> 4 consecutive cols -> b64 write
#pragma unroll
        for (int nt = 0; nt < 4; ++nt) {
            f32x4 acc = {0.f, 0.f, 0.f, 0.f};
            s16x8 w0 = *(const s16x8*)&W1L[(0 + hi) * 512 + (nt * 16 + l15) * 8];
            s16x8 w1 = *(const s16x8*)&W1L[(4 + hi) * 512 + (nt * 16 + l15) * 8];
            acc = __builtin_amdgcn_mfma_f32_16x16x32_bf16(w0, hf0, acc, 0, 0, 0);
            acc = __builtin_amdgcn_mfma_f32_16x16x32_bf16(w1, hf1, acc, 0, 0, 0);
            s16x4 tv;
#pragma unroll
            for (int r = 0; r < 4; ++r)
                tv[r] = f2bf(fmaxf(acc[r] + b1v[nt * 4 + r], 0.f));
            int wb = (l15 * 128 + (nt * 16 + hi * 4) * 2) ^ swz;
            *(s16x4*)(tl + wb) = tv;
        }

        // Re-read t as A-frags: row l15, k = hi*8+j (+32)
        int rb0 = (l15 * 128 + hi * 16) ^ swz;
        int rb1 = (l15 * 128 + hi * 16 + 64) ^ swz;
        s16x8 tf0 = *(const s16x8*)(tl + rb0);
        s16x8 tf1 = *(const s16x8*)(tl + rb1);

        // GEMM2: out tile rows hi*4+r, col nt*16+l15
        float* op = out + ((size_t)(a * N_NODES + c0 + hi * 4)) * EDIM + l15;
#pragma unroll
        for (int nt = 0; nt < 8; ++nt) {
            f32x4 acc = {0.f, 0.f, 0.f, 0.f};
            s16x8 w0 = *(const s16x8*)&W2L[(0 + hi) * 1024 + (nt * 16 + l15) * 8];
            s16x8 w1 = *(const s16x8*)&W2L[(4 + hi) * 1024 + (nt * 16 + l15) * 8];
            acc = __builtin_amdgcn_mfma_f32_16x16x32_bf16(tf0, w0, acc, 0, 0, 0);
            acc = __builtin_amdgcn_mfma_f32_16x16x32_bf16(tf1, w1, acc, 0, 0, 0);
#pragma unroll
            for (int r = 0; r < 4; ++r)
                op[(size_t)r * EDIM + nt * 16] = acc[r] + b2v[nt];
        }
    }
}

extern "C" void kernel_launch(void* const* d_in, const int* in_sizes, int n_in,
                              void* d_out, int out_size, void* d_ws, size_t ws_size,
                              hipStream_t stream) {
    const float* x   = (const float*)d_in[0];
    // d_in[1] = z (unused in forward)
    const float* Wi  = (const float*)d_in[2];
    const float* bi  = (const float*)d_in[3];
    const float* Wj  = (const float*)d_in[4];
    const float* bj  = (const float*)d_in[5];
    const float* lng = (const float*)d_in[6];
    const float* lnb = (const float*)d_in[7];
    const float* W1  = (const float*)d_in[8];
    const float* b1  = (const float*)d_in[9];
    const float* W2  = (const float*)d_in[10];
    const float* b2  = (const float*)d_in[11];
    float* out = (float*)d_out;

    float* NI = (float*)d_ws;
    float* NJ = NI + N_NODES * HDIM;

    proj_kernel<<<N_NODES / 4, 256, 0, stream>>>(x, Wi, bi, Wj, bj, NI, NJ);
    edge_kernel<<<2304, 256, 0, stream>>>(NI, NJ, lng, lnb, W1, b1, W2, b2, out);
}